// Round 12
// baseline (552.265 us; speedup 1.0000x reference)
//
#include <hip/hip_runtime.h>
#include <hip/hip_bf16.h>

#define NNODES 50000
#define NEDGES 800000
#define UNITS 64
#define NTILES (NNODES/16)        // 3125 exact
#define NB_SCAN ((NNODES+255)/256) // 196

typedef unsigned short ushort;
typedef unsigned int uint;
typedef __attribute__((ext_vector_type(8))) short bf16x8;
typedef __attribute__((ext_vector_type(4))) float floatx4;

__device__ __forceinline__ ushort f2bf(float x){
  union{float f; uint u;} v; v.f = x;
  uint r = v.u + 0x7fffu + ((v.u >> 16) & 1u);   // RNE
  return (ushort)(r >> 16);
}
__device__ __forceinline__ float bf2f(ushort h){
  union{uint u; float f;} v; v.u = ((uint)h) << 16; return v.f;
}
__device__ __forceinline__ void split8(const float* __restrict__ p, bf16x8& hi, bf16x8& lo){
  #pragma unroll
  for (int j=0;j<8;++j){
    float x = p[j];
    ushort h = f2bf(x);
    hi[j] = (short)h;
    lo[j] = (short)f2bf(x - bf2f(h));
  }
}

// DPP butterfly add (VALU pipe, no LDS): xor1, xor2, xor7, xor15 basis -> 16-lane sum
template<int CTRL>
__device__ __forceinline__ float dpp_add(float x){
  int y = __builtin_amdgcn_update_dpp(0, __float_as_int(x), CTRL, 0xF, 0xF, true);
  return x + __int_as_float(y);
}
template<int CH>
__device__ __forceinline__ float lane_sum(float p){
  p = dpp_add<0xB1>(p);    // quad_perm xor1
  p = dpp_add<0x4E>(p);    // quad_perm xor2
  p = dpp_add<0x141>(p);   // row_half_mirror = xor7
  p = dpp_add<0x140>(p);   // row_mirror = xor15
  if (CH == 64){
    p += __shfl_xor(p, 16);
    p += __shfl_xor(p, 32);
  }
  return p;
}

// ---------------- sort-by-receiver (counting sort) ----------------

__global__ void k_hist(const int* __restrict__ recv, int* __restrict__ counts){
  int e = blockIdx.x*blockDim.x + threadIdx.x;
  if (e < NEDGES) atomicAdd(&counts[recv[e]], 1);
}

__global__ void k_blocksum(const int* __restrict__ counts, int* __restrict__ bsum){
  __shared__ int red[256];
  int b = blockIdx.x, t = threadIdx.x;
  int i = b*256 + t;
  red[t] = (i < NNODES) ? counts[i] : 0;
  __syncthreads();
  for (int s=128; s>0; s>>=1){ if (t<s) red[t]+=red[t+s]; __syncthreads(); }
  if (t==0) bsum[b] = red[0];
}

__global__ void k_scantop(const int* __restrict__ bsum, int* __restrict__ bscan,
                          int* __restrict__ offsets){
  __shared__ int sh[256];
  int t = threadIdx.x;
  int own = (t < NB_SCAN) ? bsum[t] : 0;
  sh[t] = own;
  __syncthreads();
  for (int s=1; s<256; s<<=1){
    int u = (t>=s) ? sh[t-s] : 0;
    __syncthreads();
    sh[t] += u;
    __syncthreads();
  }
  if (t < NB_SCAN) bscan[t] = sh[t] - own;        // exclusive
  if (t == 0) offsets[NNODES] = sh[NB_SCAN-1];    // == NEDGES
}

__global__ void k_scanfinal(const int* __restrict__ counts, const int* __restrict__ bscan,
                            int* __restrict__ offsets, int* __restrict__ cursor){
  __shared__ int sh[256];
  int b = blockIdx.x, t = threadIdx.x;
  int i = b*256 + t;
  int own = (i < NNODES) ? counts[i] : 0;
  sh[t] = own;
  __syncthreads();
  for (int s=1; s<256; s<<=1){
    int u = (t>=s) ? sh[t-s] : 0;
    __syncthreads();
    sh[t] += u;
    __syncthreads();
  }
  if (i < NNODES){
    int excl = bscan[b] + sh[t] - own;
    offsets[i] = excl; cursor[i] = excl;
  }
}

// rank assignment (coalesced rank write) + ssend scatter (4B, cheap)
__global__ void k_scatter(const int* __restrict__ recv, const int* __restrict__ send,
                          int* __restrict__ cursor, int* __restrict__ rank,
                          int* __restrict__ ssend){
  int e = blockIdx.x*blockDim.x + threadIdx.x;
  if (e < NEDGES){
    int pos = atomicAdd(&cursor[recv[e]], 1);
    rank[e] = pos;
    ssend[pos] = send[e];
  }
}

// -------- pre-split weights into MFMA B-fragment order, bf16 hi/lo --------

__device__ __forceinline__ void packunit(const float* __restrict__ W, int r8, int col,
                                         ushort* __restrict__ H, ushort* __restrict__ L){
  bf16x8 hi, lo;
  #pragma unroll
  for (int j=0;j<8;++j){
    float x = W[(r8*8+j)*64 + col];
    ushort h = f2bf(x);
    hi[j] = (short)h;
    lo[j] = (short)f2bf(x - bf2f(h));
  }
  *(bf16x8*)(H + ((size_t)r8*64 + col)*8) = hi;
  *(bf16x8*)(L + ((size_t)r8*64 + col)*8) = lo;
}

__global__ void k_splitw(const float* __restrict__ Wq1, const float* __restrict__ Ws1,
                         const float* __restrict__ Wn1, const float* __restrict__ Wq2,
                         const float* __restrict__ Ws2, const float* __restrict__ Wn2,
                         const float* __restrict__ We1, const float* __restrict__ We2,
                         ushort* __restrict__ wsp){
  int u = blockIdx.x*blockDim.x + threadIdx.x;   // 4608 units
  if (u >= 4608) return;
  ushort* p = wsp;
  const float* W; int base;
  if      (u < 512){  W=Wq1; base=u;        p += 0;      packunit(W, base>>6, base&63, p, p+4096); return; }
  else if (u < 1024){ W=Ws1; base=u-512;    p += 8192;   packunit(W, base>>6, base&63, p, p+4096); return; }
  else if (u < 2048){ W=Wn1; base=u-1024;   p += 16384;  packunit(W, base>>6, base&63, p, p+8192); return; }
  else if (u < 2560){ W=Wq2; base=u-2048;   p += 32768;  packunit(W, base>>6, base&63, p, p+4096); return; }
  else if (u < 3072){ W=Ws2; base=u-2560;   p += 40960;  packunit(W, base>>6, base&63, p, p+4096); return; }
  else if (u < 4096){ W=Wn2; base=u-3072;   p += 49152;  packunit(W, base>>6, base&63, p, p+8192); return; }
  else if (u < 4352){ W=We1; base=u-4096;   p += 65536;  packunit(W, base>>6, base&63, p, p+2048); return; }
  else {              W=We2; base=u-4352;   p += 69632;  packunit(W, base>>6, base&63, p, p+2048); return; }
}

// -------- E1 = ef@We1, E2 = ef@We2: sequential ef reads (edge order),
// rank-scattered FULL-LINE (128 B) row writes — no efh intermediate --------

__global__ void k_gemm_e2(const float* __restrict__ ef, const int* __restrict__ rank,
                          const ushort* __restrict__ We1H, const ushort* __restrict__ We1L,
                          const ushort* __restrict__ We2H, const ushort* __restrict__ We2L,
                          ushort* __restrict__ E1, ushort* __restrict__ E2){
  int tid = threadIdx.x;
  int tile = blockIdx.x*4 + (tid >> 6);             // 50000 tiles
  int lane = tid & 63;
  int m = lane & 15, quad = lane >> 4;
  size_t base = (size_t)tile * 16;

  // A frag: ef[(base+m)][quad*8 .. +7] — fully coalesced fp32, cvt in-reg
  const float* src = ef + (base + m)*32 + quad*8;
  float4 x0 = *(const float4*)(src);
  float4 x1 = *(const float4*)(src + 4);
  bf16x8 ah;
  ah[0]=(short)f2bf(x0.x); ah[1]=(short)f2bf(x0.y);
  ah[2]=(short)f2bf(x0.z); ah[3]=(short)f2bf(x0.w);
  ah[4]=(short)f2bf(x1.x); ah[5]=(short)f2bf(x1.y);
  ah[6]=(short)f2bf(x1.z); ah[7]=(short)f2bf(x1.w);

  // sorted positions of the 4 rows this lane writes (same for 16 lanes -> L1 broadcast)
  int pos[4];
  #pragma unroll
  for (int r=0;r<4;++r) pos[r] = rank[base + quad*4 + r];

  #pragma unroll
  for (int t4 = 0; t4 < 4; ++t4){
    size_t fo = ((size_t)quad*64 + t4*16 + m)*8;
    const bf16x8 b1h = *(const bf16x8*)(We1H + fo);
    const bf16x8 b1l = *(const bf16x8*)(We1L + fo);
    const bf16x8 b2h = *(const bf16x8*)(We2H + fo);
    const bf16x8 b2l = *(const bf16x8*)(We2L + fo);
    floatx4 acc1 = {0.f,0.f,0.f,0.f};
    floatx4 acc2 = {0.f,0.f,0.f,0.f};
    acc1 = __builtin_amdgcn_mfma_f32_16x16x32_bf16(ah, b1l, acc1, 0, 0, 0);
    acc1 = __builtin_amdgcn_mfma_f32_16x16x32_bf16(ah, b1h, acc1, 0, 0, 0);
    acc2 = __builtin_amdgcn_mfma_f32_16x16x32_bf16(ah, b2l, acc2, 0, 0, 0);
    acc2 = __builtin_amdgcn_mfma_f32_16x16x32_bf16(ah, b2h, acc2, 0, 0, 0);
    #pragma unroll
    for (int r = 0; r < 4; ++r){
      size_t o = (size_t)pos[r]*64 + t4*16 + m;   // full 128B row covered over t4
      E1[o] = f2bf(acc1[r]);
      E2[o] = f2bf(acc2[r]);
    }
  }
}

// -------- node linears via MFMA: Q = h@Wq, S = h@Ws (A split, pre-split B) --------

__global__ void k_node_mm(const float* __restrict__ h,
                          const ushort* __restrict__ WqH, const ushort* __restrict__ WqL,
                          const ushort* __restrict__ WsH, const ushort* __restrict__ WsL,
                          float* __restrict__ Q, float* __restrict__ S){
  int tid = threadIdx.x;
  int tile = blockIdx.x*4 + (tid>>6);
  if (tile >= NTILES) return;
  int lane = tid & 63;
  int m = lane & 15, quad = lane >> 4;
  size_t base = (size_t)tile*16;
  floatx4 accQ[4], accS[4];
  #pragma unroll
  for (int t=0;t<4;++t){ accQ[t]=(floatx4){0,0,0,0}; accS[t]=(floatx4){0,0,0,0}; }
  #pragma unroll
  for (int ks=0; ks<2; ++ks){
    bf16x8 ah, al;
    split8(h + (base+m)*64 + ks*32 + quad*8, ah, al);
    int r8 = ks*4 + quad;
    #pragma unroll
    for (int t4=0;t4<4;++t4){
      size_t fo = ((size_t)r8*64 + t4*16 + m)*8;
      const bf16x8 bh = *(const bf16x8*)(WqH + fo);
      const bf16x8 bl = *(const bf16x8*)(WqL + fo);
      const bf16x8 ch = *(const bf16x8*)(WsH + fo);
      const bf16x8 cl = *(const bf16x8*)(WsL + fo);
      accQ[t4] = __builtin_amdgcn_mfma_f32_16x16x32_bf16(al, bh, accQ[t4],0,0,0);
      accQ[t4] = __builtin_amdgcn_mfma_f32_16x16x32_bf16(ah, bl, accQ[t4],0,0,0);
      accQ[t4] = __builtin_amdgcn_mfma_f32_16x16x32_bf16(ah, bh, accQ[t4],0,0,0);
      accS[t4] = __builtin_amdgcn_mfma_f32_16x16x32_bf16(al, ch, accS[t4],0,0,0);
      accS[t4] = __builtin_amdgcn_mfma_f32_16x16x32_bf16(ah, cl, accS[t4],0,0,0);
      accS[t4] = __builtin_amdgcn_mfma_f32_16x16x32_bf16(ah, ch, accS[t4],0,0,0);
    }
  }
  #pragma unroll
  for (int t4=0;t4<4;++t4)
    #pragma unroll
    for (int r=0;r<4;++r){
      size_t row = base + quad*4 + r;
      Q[row*64 + t4*16 + m] = accQ[t4][r];
      S[row*64 + t4*16 + m] = accS[t4][r];
    }
}

// -------- fused edge-logit + segment softmax + pool --------
// no-max softmax (logits bounded), DPP reductions, exp2 with log2e-prescaled a

template<int H>
__global__ void k_pool(const int* __restrict__ offsets, const int* __restrict__ ssend,
                       const float* __restrict__ Q, const float* __restrict__ S,
                       const ushort* __restrict__ E, const float* __restrict__ a,
                       float* __restrict__ conv){
  int tid = threadIdx.x;
  int n = blockIdx.x*4 + (tid>>6);
  uint c = tid & 63;
  if (n >= NNODES) return;
  constexpr int CH = 64 / H;
  float av = a[c] * 1.4426950408889634f;   // fold log2(e): exp(p) == exp2(p*log2e)
  float q = Q[(uint)n*64 + c];
  int beg = offsets[n], end = offsets[n+1];
  float l0=0.f,l1=0.f,l2=0.f,l3=0.f;
  float a0=0.f,a1=0.f,a2=0.f,a3=0.f;
  int i = beg;
  for (; i + 3 < end; i += 4){
    uint s0 = (uint)ssend[i],   s1 = (uint)ssend[i+1];
    uint s2 = (uint)ssend[i+2], s3 = (uint)ssend[i+3];
    float sv0 = S[s0*64u + c];
    float sv1 = S[s1*64u + c];
    float sv2 = S[s2*64u + c];
    float sv3 = S[s3*64u + c];
    float ev0 = bf2f(E[(uint)(i+0)*64u + c]);
    float ev1 = bf2f(E[(uint)(i+1)*64u + c]);
    float ev2 = bf2f(E[(uint)(i+2)*64u + c]);
    float ev3 = bf2f(E[(uint)(i+3)*64u + c]);
    float k0 = sv0+ev0, k1 = sv1+ev1, k2 = sv2+ev2, k3 = sv3+ev3;
    float f0 = q+k0, f1 = q+k1, f2 = q+k2, f3 = q+k3;
    f0 = fmaxf(f0, 0.2f*f0); f1 = fmaxf(f1, 0.2f*f1);
    f2 = fmaxf(f2, 0.2f*f2); f3 = fmaxf(f3, 0.2f*f3);
    float p0 = lane_sum<CH>(f0*av);
    float p1 = lane_sum<CH>(f1*av);
    float p2 = lane_sum<CH>(f2*av);
    float p3 = lane_sum<CH>(f3*av);
    float w0 = exp2f(p0), w1 = exp2f(p1), w2 = exp2f(p2), w3 = exp2f(p3);
    l0 += w0; l1 += w1; l2 += w2; l3 += w3;
    a0 = fmaf(w0, k0, a0); a1 = fmaf(w1, k1, a1);
    a2 = fmaf(w2, k2, a2); a3 = fmaf(w3, k3, a3);
  }
  for (; i < end; ++i){
    uint s0 = (uint)ssend[i];
    float k0 = S[s0*64u + c] + bf2f(E[(uint)i*64u + c]);
    float f0 = q + k0;
    f0 = fmaxf(f0, 0.2f*f0);
    float w0 = exp2f(lane_sum<CH>(f0*av));
    l0 += w0;
    a0 = fmaf(w0, k0, a0);
  }
  float l = (l0+l1) + (l2+l3);
  float acc = (a0+a1) + (a2+a3);
  float res = (l > 0.f) ? acc/l : 0.f;
  conv[(uint)n*64 + c] = fmaxf(res, 0.f);
}

// -------- node update via MFMA: h' = relu([h,conv]@Wn + bn); opt. fused readout ----

template<bool READOUT>
__global__ void k_update(const float* __restrict__ h, const float* __restrict__ conv,
                         const ushort* __restrict__ WnH, const ushort* __restrict__ WnL,
                         const float* __restrict__ bn,
                         float* __restrict__ hout, const float* __restrict__ Wd,
                         const float* __restrict__ bd, float* __restrict__ out){
  int tid = threadIdx.x;
  int tile = blockIdx.x*4 + (tid>>6);
  if (tile >= NTILES) return;
  int lane = tid & 63;
  int m = lane & 15, quad = lane >> 4;
  size_t base = (size_t)tile*16;
  floatx4 acc[4];
  #pragma unroll
  for (int t=0;t<4;++t) acc[t]=(floatx4){0,0,0,0};
  #pragma unroll
  for (int ks=0; ks<4; ++ks){
    bf16x8 ah, al;
    const float* src = (ks < 2) ? (h    + (base+m)*64 + ks*32     + quad*8)
                                : (conv + (base+m)*64 + (ks-2)*32 + quad*8);
    split8(src, ah, al);
    int r8 = ks*4 + quad;
    #pragma unroll
    for (int t4=0;t4<4;++t4){
      size_t fo = ((size_t)r8*64 + t4*16 + m)*8;
      const bf16x8 bh = *(const bf16x8*)(WnH + fo);
      const bf16x8 bl = *(const bf16x8*)(WnL + fo);
      acc[t4] = __builtin_amdgcn_mfma_f32_16x16x32_bf16(al, bh, acc[t4],0,0,0);
      acc[t4] = __builtin_amdgcn_mfma_f32_16x16x32_bf16(ah, bl, acc[t4],0,0,0);
      acc[t4] = __builtin_amdgcn_mfma_f32_16x16x32_bf16(ah, bh, acc[t4],0,0,0);
    }
  }
  if (!READOUT){
    #pragma unroll
    for (int t4=0;t4<4;++t4){
      float b = bn[t4*16 + m];
      #pragma unroll
      for (int r=0;r<4;++r)
        hout[(base + quad*4 + r)*64 + t4*16 + m] = fmaxf(acc[t4][r] + b, 0.f);
    }
  } else {
    float bv[4], wd[4];
    #pragma unroll
    for (int t4=0;t4<4;++t4){ bv[t4] = bn[t4*16+m]; wd[t4] = Wd[t4*16+m]; }
    #pragma unroll
    for (int r=0;r<4;++r){
      float v = 0.f;
      #pragma unroll
      for (int t4=0;t4<4;++t4) v += fmaxf(acc[t4][r] + bv[t4], 0.f) * wd[t4];
      #pragma unroll
      for (int off=1; off<16; off<<=1) v += __shfl_xor(v, off);  // stays in quad
      if (m == 0) out[base + quad*4 + r] = v + bd[0];
    }
  }
}

extern "C" void kernel_launch(void* const* d_in, const int* in_sizes, int n_in,
                              void* d_out, int out_size, void* d_ws, size_t ws_size,
                              hipStream_t stream){
  const float* node_feats = (const float*)d_in[0];
  const float* edge_feats = (const float*)d_in[1];
  const int*   senders    = (const int*)d_in[2];
  const int*   receivers  = (const int*)d_in[3];
  const float* Wq1 = (const float*)d_in[4];
  const float* Ws1 = (const float*)d_in[5];
  const float* We1 = (const float*)d_in[6];
  const float* a1  = (const float*)d_in[7];
  const float* Wn1 = (const float*)d_in[8];
  const float* bn1 = (const float*)d_in[9];
  const float* Wq2 = (const float*)d_in[10];
  const float* Ws2 = (const float*)d_in[11];
  const float* We2 = (const float*)d_in[12];
  const float* a2  = (const float*)d_in[13];
  const float* Wn2 = (const float*)d_in[14];
  const float* bn2 = (const float*)d_in[15];
  const float* Wd  = (const float*)d_in[16];
  const float* bd  = (const float*)d_in[17];
  float* out = (float*)d_out;

  // workspace layout (~264 MB of the 409.6 MB ws)
  char* base = (char*)d_ws;
  const size_t NF = (size_t)NNODES*64;
  float* Q     = (float*)base; base += NF*4;
  float* S     = (float*)base; base += NF*4;
  float* conv  = (float*)base; base += NF*4;
  float* h1    = (float*)base; base += NF*4;
  ushort* E1   = (ushort*)base; base += (size_t)NEDGES*64*2;    // 102.4 MB
  ushort* E2   = (ushort*)base; base += (size_t)NEDGES*64*2;    // 102.4 MB
  int* counts     = (int*)base; base += (size_t)NNODES*4;
  int* offsets    = (int*)base; base += (size_t)(NNODES+1)*4;
  int* cursor     = (int*)base; base += (size_t)NNODES*4;
  int* rank       = (int*)base; base += (size_t)NEDGES*4;
  int* ssend      = (int*)base; base += (size_t)NEDGES*4;
  ushort* wsp     = (ushort*)base; base += (size_t)73728*2;     // pre-split weights
  int* bsum       = (int*)base; base += (size_t)NB_SCAN*4;
  int* bscan      = (int*)base; base += (size_t)NB_SCAN*4;

  if (ws_size < (size_t)(base - (char*)d_ws)) return;  // tripwire: out stays 0

  const ushort *Wq1H=wsp+0,     *Wq1L=wsp+4096,  *Ws1H=wsp+8192,  *Ws1L=wsp+12288;
  const ushort *Wn1H=wsp+16384, *Wn1L=wsp+24576, *Wq2H=wsp+32768, *Wq2L=wsp+36864;
  const ushort *Ws2H=wsp+40960, *Ws2L=wsp+45056, *Wn2H=wsp+49152, *Wn2L=wsp+57344;
  const ushort *We1H=wsp+65536, *We1L=wsp+67584, *We2H=wsp+69632, *We2L=wsp+71680;

  dim3 b256(256);
  int nb_node = (NNODES+3)/4;
  int nb_tile = (NTILES+3)/4;
  int nb_gemm = (NEDGES/16+3)/4;
  int nb_edge = (NEDGES+255)/256;

  // weight pre-split (independent of everything else)
  k_splitw   <<<(4608+255)/256, b256, 0, stream>>>(Wq1,Ws1,Wn1,Wq2,Ws2,Wn2,We1,We2, wsp);

  // counting sort by receiver (rank + ssend; no feature permute pass)
  hipMemsetAsync(counts, 0, (size_t)NNODES*4, stream);
  k_hist     <<<nb_edge, b256, 0, stream>>>(receivers, counts);
  k_blocksum <<<NB_SCAN, b256, 0, stream>>>(counts, bsum);
  k_scantop  <<<1, b256, 0, stream>>>(bsum, bscan, offsets);
  k_scanfinal<<<NB_SCAN, b256, 0, stream>>>(counts, bscan, offsets, cursor);
  k_scatter  <<<nb_edge, b256, 0, stream>>>(receivers, senders, cursor, rank, ssend);

  // both layers' edge GEMMs: sequential ef reads, rank-scattered full-line writes
  k_gemm_e2 <<<nb_gemm, b256, 0, stream>>>(edge_feats, rank, We1H,We1L, We2H,We2L, E1, E2);

  // ---- layer 1 (H=4) ----
  k_node_mm <<<nb_tile, b256, 0, stream>>>(node_feats, Wq1H,Wq1L, Ws1H,Ws1L, Q, S);
  k_pool<4> <<<nb_node, b256, 0, stream>>>(offsets, ssend, Q, S, E1, a1, conv);
  k_update<false><<<nb_tile, b256, 0, stream>>>(node_feats, conv, Wn1H, Wn1L, bn1, h1,
                                                nullptr, nullptr, nullptr);

  // ---- layer 2 (H=1) + fused readout ----
  k_node_mm <<<nb_tile, b256, 0, stream>>>(h1, Wq2H,Wq2L, Ws2H,Ws2L, Q, S);
  k_pool<1> <<<nb_node, b256, 0, stream>>>(offsets, ssend, Q, S, E2, a2, conv);
  k_update<true><<<nb_tile, b256, 0, stream>>>(h1, conv, Wn2H, Wn2L, bn2, nullptr,
                                               Wd, bd, out);
}

// Round 13
// 481.664 us; speedup vs baseline: 1.1466x; 1.1466x over previous
//
#include <hip/hip_runtime.h>
#include <hip/hip_bf16.h>

#define NNODES 50000
#define NEDGES 800000
#define UNITS 64
#define NTILES (NNODES/16)         // 3125 exact
#define NB_SCAN ((NNODES+255)/256) // 196
#define NB_GEMM (NEDGES/16/4)      // 12500
#define NB_NODE ((NTILES+3)/4)     // 782
#define NB_HIST ((NEDGES+255)/256) // 3125

typedef unsigned short ushort;
typedef unsigned int uint;
typedef __attribute__((ext_vector_type(8))) short bf16x8;
typedef __attribute__((ext_vector_type(4))) float floatx4;
typedef __attribute__((ext_vector_type(4))) ushort ushort4_t;

__device__ __forceinline__ ushort f2bf(float x){
  union{float f; uint u;} v; v.f = x;
  uint r = v.u + 0x7fffu + ((v.u >> 16) & 1u);   // RNE
  return (ushort)(r >> 16);
}
__device__ __forceinline__ float bf2f(ushort h){
  union{uint u; float f;} v; v.u = ((uint)h) << 16; return v.f;
}
__device__ __forceinline__ void split8(const float* __restrict__ p, bf16x8& hi, bf16x8& lo){
  #pragma unroll
  for (int j=0;j<8;++j){
    float x = p[j];
    ushort h = f2bf(x);
    hi[j] = (short)h;
    lo[j] = (short)f2bf(x - bf2f(h));
  }
}

// DPP butterfly add (VALU pipe, no LDS): xor1, xor2, xor7, xor15 basis -> 16-lane sum
template<int CTRL>
__device__ __forceinline__ float dpp_add(float x){
  int y = __builtin_amdgcn_update_dpp(0, __float_as_int(x), CTRL, 0xF, 0xF, true);
  return x + __int_as_float(y);
}
template<int CH>
__device__ __forceinline__ float lane_sum(float p){
  p = dpp_add<0xB1>(p);    // quad_perm xor1
  p = dpp_add<0x4E>(p);    // quad_perm xor2
  p = dpp_add<0x141>(p);   // row_half_mirror = xor7
  p = dpp_add<0x140>(p);   // row_mirror = xor15
  if (CH == 64){
    p += __shfl_xor(p, 16);
    p += __shfl_xor(p, 32);
  }
  return p;
}

// -------- weight pre-split unit (MFMA B-fragment order, bf16 hi/lo) --------

__device__ __forceinline__ void packunit(const float* __restrict__ W, int r8, int col,
                                         ushort* __restrict__ H, ushort* __restrict__ L){
  bf16x8 hi, lo;
  #pragma unroll
  for (int j=0;j<8;++j){
    float x = W[(r8*8+j)*64 + col];
    ushort h = f2bf(x);
    hi[j] = (short)h;
    lo[j] = (short)f2bf(x - bf2f(h));
  }
  *(bf16x8*)(H + ((size_t)r8*64 + col)*8) = hi;
  *(bf16x8*)(L + ((size_t)r8*64 + col)*8) = lo;
}

// -------- fused: hist (blocks 0..NB_HIST) + splitw (rest) --------

__global__ void k_init(const int* __restrict__ recv, int* __restrict__ counts,
                       const float* __restrict__ Wq1, const float* __restrict__ Ws1,
                       const float* __restrict__ Wn1, const float* __restrict__ Wq2,
                       const float* __restrict__ Ws2, const float* __restrict__ Wn2,
                       const float* __restrict__ We1, const float* __restrict__ We2,
                       ushort* __restrict__ wsp){
  if (blockIdx.x < NB_HIST){
    int e = blockIdx.x*blockDim.x + threadIdx.x;
    if (e < NEDGES) atomicAdd(&counts[recv[e]], 1);
    return;
  }
  int u = (blockIdx.x - NB_HIST)*blockDim.x + threadIdx.x;   // 4608 units
  if (u >= 4608) return;
  ushort* p = wsp;
  const float* W; int base;
  if      (u < 512){  W=Wq1; base=u;        p += 0;      packunit(W, base>>6, base&63, p, p+4096); return; }
  else if (u < 1024){ W=Ws1; base=u-512;    p += 8192;   packunit(W, base>>6, base&63, p, p+4096); return; }
  else if (u < 2048){ W=Wn1; base=u-1024;   p += 16384;  packunit(W, base>>6, base&63, p, p+8192); return; }
  else if (u < 2560){ W=Wq2; base=u-2048;   p += 32768;  packunit(W, base>>6, base&63, p, p+4096); return; }
  else if (u < 3072){ W=Ws2; base=u-2560;   p += 40960;  packunit(W, base>>6, base&63, p, p+4096); return; }
  else if (u < 4096){ W=Wn2; base=u-3072;   p += 49152;  packunit(W, base>>6, base&63, p, p+8192); return; }
  else if (u < 4352){ W=We1; base=u-4096;   p += 65536;  packunit(W, base>>6, base&63, p, p+2048); return; }
  else {              W=We2; base=u-4352;   p += 69632;  packunit(W, base>>6, base&63, p, p+2048); return; }
}

// ---------------- hierarchical exclusive scan ----------------

__global__ void k_blocksum(const int* __restrict__ counts, int* __restrict__ bsum){
  __shared__ int red[256];
  int b = blockIdx.x, t = threadIdx.x;
  int i = b*256 + t;
  red[t] = (i < NNODES) ? counts[i] : 0;
  __syncthreads();
  for (int s=128; s>0; s>>=1){ if (t<s) red[t]+=red[t+s]; __syncthreads(); }
  if (t==0) bsum[b] = red[0];
}

__global__ void k_scantop(const int* __restrict__ bsum, int* __restrict__ bscan,
                          int* __restrict__ offsets){
  __shared__ int sh[256];
  int t = threadIdx.x;
  int own = (t < NB_SCAN) ? bsum[t] : 0;
  sh[t] = own;
  __syncthreads();
  for (int s=1; s<256; s<<=1){
    int u = (t>=s) ? sh[t-s] : 0;
    __syncthreads();
    sh[t] += u;
    __syncthreads();
  }
  if (t < NB_SCAN) bscan[t] = sh[t] - own;        // exclusive
  if (t == 0) offsets[NNODES] = sh[NB_SCAN-1];    // == NEDGES
}

__global__ void k_scanfinal(const int* __restrict__ counts, const int* __restrict__ bscan,
                            int* __restrict__ offsets, int* __restrict__ cursor){
  __shared__ int sh[256];
  int b = blockIdx.x, t = threadIdx.x;
  int i = b*256 + t;
  int own = (i < NNODES) ? counts[i] : 0;
  sh[t] = own;
  __syncthreads();
  for (int s=1; s<256; s<<=1){
    int u = (t>=s) ? sh[t-s] : 0;
    __syncthreads();
    sh[t] += u;
    __syncthreads();
  }
  if (i < NNODES){
    int excl = bscan[b] + sh[t] - own;
    offsets[i] = excl; cursor[i] = excl;
  }
}

// scatter: sorted_eid + ssend at sorted pos (r8-proven)
__global__ void k_scatter(const int* __restrict__ recv, const int* __restrict__ send,
                          int* __restrict__ cursor, int* __restrict__ sorted_eid,
                          int* __restrict__ ssend){
  int e = blockIdx.x*blockDim.x + threadIdx.x;
  if (e < NEDGES){
    int pos = atomicAdd(&cursor[recv[e]], 1);
    sorted_eid[pos] = e;
    ssend[pos] = send[e];
  }
}

// permute: 8 threads/row, float4 gather in, ushort4 sequential-ish out (r8-proven)
__global__ void k_permute(const float* __restrict__ ef, const int* __restrict__ sorted_eid,
                          ushort* __restrict__ efh){
  int t = blockIdx.x*blockDim.x + threadIdx.x;     // NEDGES*8
  if (t >= NEDGES*8) return;
  int i = t >> 3, d4 = t & 7;
  int e = sorted_eid[i];
  float4 x = *(const float4*)(ef + (size_t)e*32 + d4*4);
  ushort4_t o;
  o.x = f2bf(x.x); o.y = f2bf(x.y); o.z = f2bf(x.z); o.w = f2bf(x.w);
  *(ushort4_t*)(efh + (size_t)i*32 + d4*4) = o;
}

// -------- fused per-layer MFMA: E = efh@We (blocks < NB_GEMM) and
//          Q = h@Wq (fp32), Sb = h@Ws (bf16) (remaining blocks) --------

__global__ void k_mme(const ushort* __restrict__ efh,
                      const ushort* __restrict__ WeH, const ushort* __restrict__ WeL,
                      ushort* __restrict__ E,
                      const float* __restrict__ h,
                      const ushort* __restrict__ WqH, const ushort* __restrict__ WqL,
                      const ushort* __restrict__ WsH, const ushort* __restrict__ WsL,
                      float* __restrict__ Q, ushort* __restrict__ Sb){
  int tid = threadIdx.x;
  int lane = tid & 63;
  int m = lane & 15, quad = lane >> 4;

  if (blockIdx.x < NB_GEMM){
    int tile = blockIdx.x*4 + (tid >> 6);           // 50000 tiles
    size_t base = (size_t)tile * 16;
    const bf16x8 ah = *(const bf16x8*)(efh + (base + m)*32 + quad*8);
    #pragma unroll
    for (int t4 = 0; t4 < 4; ++t4){
      size_t fo = ((size_t)quad*64 + t4*16 + m)*8;
      const bf16x8 bh = *(const bf16x8*)(WeH + fo);
      const bf16x8 bl = *(const bf16x8*)(WeL + fo);
      floatx4 acc = {0.f,0.f,0.f,0.f};
      acc = __builtin_amdgcn_mfma_f32_16x16x32_bf16(ah, bl, acc, 0, 0, 0);
      acc = __builtin_amdgcn_mfma_f32_16x16x32_bf16(ah, bh, acc, 0, 0, 0);
      #pragma unroll
      for (int r = 0; r < 4; ++r)
        E[(base + quad*4 + r)*64 + t4*16 + m] = f2bf(acc[r]);
    }
    return;
  }

  int tile = (int)(blockIdx.x - NB_GEMM)*4 + (tid>>6);
  if (tile >= NTILES) return;
  size_t base = (size_t)tile*16;
  floatx4 accQ[4], accS[4];
  #pragma unroll
  for (int t=0;t<4;++t){ accQ[t]=(floatx4){0,0,0,0}; accS[t]=(floatx4){0,0,0,0}; }
  #pragma unroll
  for (int ks=0; ks<2; ++ks){
    bf16x8 ah, al;
    split8(h + (base+m)*64 + ks*32 + quad*8, ah, al);
    int r8 = ks*4 + quad;
    #pragma unroll
    for (int t4=0;t4<4;++t4){
      size_t fo = ((size_t)r8*64 + t4*16 + m)*8;
      const bf16x8 bh = *(const bf16x8*)(WqH + fo);
      const bf16x8 bl = *(const bf16x8*)(WqL + fo);
      const bf16x8 ch = *(const bf16x8*)(WsH + fo);
      const bf16x8 cl = *(const bf16x8*)(WsL + fo);
      accQ[t4] = __builtin_amdgcn_mfma_f32_16x16x32_bf16(al, bh, accQ[t4],0,0,0);
      accQ[t4] = __builtin_amdgcn_mfma_f32_16x16x32_bf16(ah, bl, accQ[t4],0,0,0);
      accQ[t4] = __builtin_amdgcn_mfma_f32_16x16x32_bf16(ah, bh, accQ[t4],0,0,0);
      accS[t4] = __builtin_amdgcn_mfma_f32_16x16x32_bf16(al, ch, accS[t4],0,0,0);
      accS[t4] = __builtin_amdgcn_mfma_f32_16x16x32_bf16(ah, cl, accS[t4],0,0,0);
      accS[t4] = __builtin_amdgcn_mfma_f32_16x16x32_bf16(ah, ch, accS[t4],0,0,0);
    }
  }
  #pragma unroll
  for (int t4=0;t4<4;++t4)
    #pragma unroll
    for (int r=0;r<4;++r){
      size_t row = base + quad*4 + r;
      Q[row*64 + t4*16 + m]  = accQ[t4][r];
      Sb[row*64 + t4*16 + m] = f2bf(accS[t4][r]);
    }
}

// -------- fused edge-logit + segment softmax + pool --------
// no-max softmax, DPP reductions, exp2(log2e-prescaled a), bf16 S,
// 8-way unrolled main loop (16 outstanding gathers), 4-way + 1-way tail

template<int H>
__global__ void k_pool(const int* __restrict__ offsets, const int* __restrict__ ssend,
                       const float* __restrict__ Q, const ushort* __restrict__ Sb,
                       const ushort* __restrict__ E, const float* __restrict__ a,
                       float* __restrict__ conv){
  int tid = threadIdx.x;
  int n = blockIdx.x*4 + (tid>>6);
  uint c = tid & 63;
  if (n >= NNODES) return;
  constexpr int CH = 64 / H;
  float av = a[c] * 1.4426950408889634f;
  float q = Q[(uint)n*64 + c];
  int beg = offsets[n], end = offsets[n+1];
  float lsum[8], asum[8];
  #pragma unroll
  for (int u=0;u<8;++u){ lsum[u]=0.f; asum[u]=0.f; }
  int i = beg;
  for (; i + 7 < end; i += 8){
    float k[8];
    #pragma unroll
    for (int u=0;u<8;++u){
      uint s = (uint)ssend[i+u];
      k[u] = bf2f(Sb[s*64u + c]) + bf2f(E[(uint)(i+u)*64u + c]);
    }
    #pragma unroll
    for (int u=0;u<8;++u){
      float f = q + k[u];
      f = fmaxf(f, 0.2f*f);                       // leaky_relu 0.2
      float w = exp2f(lane_sum<CH>(f*av));
      lsum[u] += w;
      asum[u] = fmaf(w, k[u], asum[u]);
    }
  }
  if (i + 3 < end){
    float k[4];
    #pragma unroll
    for (int u=0;u<4;++u){
      uint s = (uint)ssend[i+u];
      k[u] = bf2f(Sb[s*64u + c]) + bf2f(E[(uint)(i+u)*64u + c]);
    }
    #pragma unroll
    for (int u=0;u<4;++u){
      float f = q + k[u];
      f = fmaxf(f, 0.2f*f);
      float w = exp2f(lane_sum<CH>(f*av));
      lsum[u] += w;
      asum[u] = fmaf(w, k[u], asum[u]);
    }
    i += 4;
  }
  for (; i < end; ++i){
    uint s = (uint)ssend[i];
    float k0 = bf2f(Sb[s*64u + c]) + bf2f(E[(uint)i*64u + c]);
    float f = q + k0;
    f = fmaxf(f, 0.2f*f);
    float w = exp2f(lane_sum<CH>(f*av));
    lsum[0] += w;
    asum[0] = fmaf(w, k0, asum[0]);
  }
  float l   = ((lsum[0]+lsum[1])+(lsum[2]+lsum[3])) + ((lsum[4]+lsum[5])+(lsum[6]+lsum[7]));
  float acc = ((asum[0]+asum[1])+(asum[2]+asum[3])) + ((asum[4]+asum[5])+(asum[6]+asum[7]));
  float res = (l > 0.f) ? acc/l : 0.f;
  conv[(uint)n*64 + c] = fmaxf(res, 0.f);
}

// -------- node update via MFMA: h' = relu([h,conv]@Wn + bn); opt. fused readout ----

template<bool READOUT>
__global__ void k_update(const float* __restrict__ h, const float* __restrict__ conv,
                         const ushort* __restrict__ WnH, const ushort* __restrict__ WnL,
                         const float* __restrict__ bn,
                         float* __restrict__ hout, const float* __restrict__ Wd,
                         const float* __restrict__ bd, float* __restrict__ out){
  int tid = threadIdx.x;
  int tile = blockIdx.x*4 + (tid>>6);
  if (tile >= NTILES) return;
  int lane = tid & 63;
  int m = lane & 15, quad = lane >> 4;
  size_t base = (size_t)tile*16;
  floatx4 acc[4];
  #pragma unroll
  for (int t=0;t<4;++t) acc[t]=(floatx4){0,0,0,0};
  #pragma unroll
  for (int ks=0; ks<4; ++ks){
    bf16x8 ah, al;
    const float* src = (ks < 2) ? (h    + (base+m)*64 + ks*32     + quad*8)
                                : (conv + (base+m)*64 + (ks-2)*32 + quad*8);
    split8(src, ah, al);
    int r8 = ks*4 + quad;
    #pragma unroll
    for (int t4=0;t4<4;++t4){
      size_t fo = ((size_t)r8*64 + t4*16 + m)*8;
      const bf16x8 bh = *(const bf16x8*)(WnH + fo);
      const bf16x8 bl = *(const bf16x8*)(WnL + fo);
      acc[t4] = __builtin_amdgcn_mfma_f32_16x16x32_bf16(al, bh, acc[t4],0,0,0);
      acc[t4] = __builtin_amdgcn_mfma_f32_16x16x32_bf16(ah, bl, acc[t4],0,0,0);
      acc[t4] = __builtin_amdgcn_mfma_f32_16x16x32_bf16(ah, bh, acc[t4],0,0,0);
    }
  }
  if (!READOUT){
    #pragma unroll
    for (int t4=0;t4<4;++t4){
      float b = bn[t4*16 + m];
      #pragma unroll
      for (int r=0;r<4;++r)
        hout[(base + quad*4 + r)*64 + t4*16 + m] = fmaxf(acc[t4][r] + b, 0.f);
    }
  } else {
    float bv[4], wd[4];
    #pragma unroll
    for (int t4=0;t4<4;++t4){ bv[t4] = bn[t4*16+m]; wd[t4] = Wd[t4*16+m]; }
    #pragma unroll
    for (int r=0;r<4;++r){
      float v = 0.f;
      #pragma unroll
      for (int t4=0;t4<4;++t4) v += fmaxf(acc[t4][r] + bv[t4], 0.f) * wd[t4];
      #pragma unroll
      for (int off=1; off<16; off<<=1) v += __shfl_xor(v, off);  // stays in quad
      if (m == 0) out[base + quad*4 + r] = v + bd[0];
    }
  }
}

extern "C" void kernel_launch(void* const* d_in, const int* in_sizes, int n_in,
                              void* d_out, int out_size, void* d_ws, size_t ws_size,
                              hipStream_t stream){
  const float* node_feats = (const float*)d_in[0];
  const float* edge_feats = (const float*)d_in[1];
  const int*   senders    = (const int*)d_in[2];
  const int*   receivers  = (const int*)d_in[3];
  const float* Wq1 = (const float*)d_in[4];
  const float* Ws1 = (const float*)d_in[5];
  const float* We1 = (const float*)d_in[6];
  const float* a1  = (const float*)d_in[7];
  const float* Wn1 = (const float*)d_in[8];
  const float* bn1 = (const float*)d_in[9];
  const float* Wq2 = (const float*)d_in[10];
  const float* Ws2 = (const float*)d_in[11];
  const float* We2 = (const float*)d_in[12];
  const float* a2  = (const float*)d_in[13];
  const float* Wn2 = (const float*)d_in[14];
  const float* bn2 = (const float*)d_in[15];
  const float* Wd  = (const float*)d_in[16];
  const float* bd  = (const float*)d_in[17];
  float* out = (float*)d_out;

  // workspace layout (~205 MB of the 409.6 MB ws)
  char* base = (char*)d_ws;
  const size_t NF = (size_t)NNODES*64;
  float*  Q    = (float*)base;  base += NF*4;                   // 12.8 MB
  ushort* Sb   = (ushort*)base; base += NF*2;                   //  6.4 MB (bf16)
  float*  conv = (float*)base;  base += NF*4;                   // 12.8 MB
  float*  h1   = (float*)base;  base += NF*4;                   // 12.8 MB
  ushort* efh  = (ushort*)base; base += (size_t)NEDGES*32*2;    // 51.2 MB
  ushort* E    = (ushort*)base; base += (size_t)NEDGES*64*2;    // 102.4 MB (per-layer reuse)
  int* counts     = (int*)base; base += (size_t)NNODES*4;
  int* offsets    = (int*)base; base += (size_t)(NNODES+1)*4;
  int* cursor     = (int*)base; base += (size_t)NNODES*4;
  int* sorted_eid = (int*)base; base += (size_t)NEDGES*4;
  int* ssend      = (int*)base; base += (size_t)NEDGES*4;
  ushort* wsp     = (ushort*)base; base += (size_t)73728*2;     // pre-split weights
  int* bsum       = (int*)base; base += (size_t)NB_SCAN*4;
  int* bscan      = (int*)base; base += (size_t)NB_SCAN*4;

  if (ws_size < (size_t)(base - (char*)d_ws)) return;  // tripwire: out stays 0

  const ushort *Wq1H=wsp+0,     *Wq1L=wsp+4096,  *Ws1H=wsp+8192,  *Ws1L=wsp+12288;
  const ushort *Wn1H=wsp+16384, *Wn1L=wsp+24576, *Wq2H=wsp+32768, *Wq2L=wsp+36864;
  const ushort *Ws2H=wsp+40960, *Ws2L=wsp+45056, *Wn2H=wsp+49152, *Wn2L=wsp+57344;
  const ushort *We1H=wsp+65536, *We1L=wsp+67584, *We2H=wsp+69632, *We2L=wsp+71680;

  dim3 b256(256);
  int nb_node = (NNODES+3)/4;
  int nb_edge = (NEDGES+255)/256;

  // 1: zero counts
  hipMemsetAsync(counts, 0, (size_t)NNODES*4, stream);
  // 2: fused hist + weight pre-split
  k_init     <<<NB_HIST + (4608+255)/256, b256, 0, stream>>>(receivers, counts,
                Wq1,Ws1,Wn1,Wq2,Ws2,Wn2,We1,We2, wsp);
  // 3-5: scan
  k_blocksum <<<NB_SCAN, b256, 0, stream>>>(counts, bsum);
  k_scantop  <<<1, b256, 0, stream>>>(bsum, bscan, offsets);
  k_scanfinal<<<NB_SCAN, b256, 0, stream>>>(counts, bscan, offsets, cursor);
  // 6: scatter (sorted_eid + ssend)
  k_scatter  <<<nb_edge, b256, 0, stream>>>(receivers, senders, cursor, sorted_eid, ssend);
  // 7: gather-permute ef -> efh (sorted, bf16)
  k_permute  <<<(NEDGES*8+255)/256, b256, 0, stream>>>(edge_feats, sorted_eid, efh);

  // ---- layer 1 (H=4) ----
  k_mme <<<NB_GEMM+NB_NODE, b256, 0, stream>>>(efh, We1H, We1L, E,
          node_feats, Wq1H,Wq1L, Ws1H,Ws1L, Q, Sb);
  k_pool<4> <<<nb_node, b256, 0, stream>>>(offsets, ssend, Q, Sb, E, a1, conv);
  k_update<false><<<NB_NODE, b256, 0, stream>>>(node_feats, conv, Wn1H, Wn1L, bn1, h1,
                                                nullptr, nullptr, nullptr);

  // ---- layer 2 (H=1) + fused readout ----
  k_mme <<<NB_GEMM+NB_NODE, b256, 0, stream>>>(efh, We2H, We2L, E,
          h1, Wq2H,Wq2L, Ws2H,Ws2L, Q, Sb);
  k_pool<1> <<<nb_node, b256, 0, stream>>>(offsets, ssend, Q, Sb, E, a2, conv);
  k_update<true><<<NB_NODE, b256, 0, stream>>>(h1, conv, Wn2H, Wn2L, bn2, nullptr,
                                               Wd, bd, out);
}